// Round 8
// baseline (104.843 us; speedup 1.0000x reference)
//
#include <hip/hip_runtime.h>
#include <hip/hip_bf16.h>

// Sizes fixed by the reference problem.
#define B_N   4096
#define D_N   1024
#define P_N   64
#define C0_N  16
#define C1_N  32
#define NC_N  48    // C0 + C1 concatenated

// parent GEMM K-split
#define KC1   16
#define DKC1  64
#define L1S   68     // 64+4: 16B-aligned rows; rows 16 apart -> 2-way bank alias (free)

// child GEMM K-split
#define KC2   8
#define DKC2  128
#define L2S   132    // 128+4: same bank math

// Tie physics: fp32 softmax probs can only tie when the true logit gap is
// <~2e-7 (exp ulp 6e-8 near 1.0; prob ulp 1.9e-9 x s~64 = 1.2e-7; exp
// rounding +-6e-8). Our fp32 gap estimate is accurate to ~1e-9. tau=1e-6
// gives 5x margin and flags only ~0.6% of rows.
#define GAP_TAU 1e-6f
#define NEG_INF (-3.402823466e38f)

// ---------------------------------------------------------------------------
// Kernel A: parent-logit partials, register-tiled.
// Block = 64 rows x 64 parents x one 64-deep K-chunk; 256 threads.
// Thread (pt=tid&15, rt=tid>>4): parents {pt+16i} x rows {rt+16j}, i,j<4.
// Partials layout [row][kc][p] (row stride KC1*P_N = 1024 floats): a row's
// 16 partials are one contiguous 4KB block -> reader (route) streams one
// page per row instead of touching 16 pages 1MB apart (r7: 18us/wave).
// Block (0,0) zeroes counts (replaces a memset dispatch).
// ---------------------------------------------------------------------------
__global__ __launch_bounds__(256, 4)
void hc_parent_partial(const float* __restrict__ x,
                       const float* __restrict__ pw,
                       float* __restrict__ partials,
                       int* __restrict__ counts) {
    __shared__ float xs[64 * L1S];
    __shared__ float ws[P_N * L1S];

    const int tid = threadIdx.x;
    if (blockIdx.x == 0 && blockIdx.y == 0 && tid < P_N) counts[tid] = 0;

    const int r0 = blockIdx.x * 64;
    const int d0 = blockIdx.y * DKC1;

    // stage x: 64 rows x 64 floats = 1024 float4, 4 per thread
    #pragma unroll
    for (int k = 0; k < 4; ++k) {
        const int f  = tid + 256 * k;
        const int r  = f >> 4;
        const int dp = (f & 15) * 4;
        *(float4*)&xs[r * L1S + dp] =
            *(const float4*)&x[(size_t)(r0 + r) * D_N + d0 + dp];
    }
    // stage W chunk: 64 rows x 64 floats = 1024 float4, 4 per thread
    #pragma unroll
    for (int k = 0; k < 4; ++k) {
        const int f  = tid + 256 * k;
        const int r  = f >> 4;
        const int dp = (f & 15) * 4;
        *(float4*)&ws[r * L1S + dp] =
            *(const float4*)&pw[(size_t)r * D_N + d0 + dp];
    }
    __syncthreads();

    const int pt = tid & 15;
    const int rt = tid >> 4;   // 0..15

    float acc[4][4] = {};      // [i: parent][j: row]
    #pragma unroll
    for (int d = 0; d < DKC1; d += 4) {
        float4 w4[4], x4[4];
        #pragma unroll
        for (int i = 0; i < 4; ++i)
            w4[i] = *(const float4*)&ws[(pt + 16 * i) * L1S + d];
        #pragma unroll
        for (int j = 0; j < 4; ++j)
            x4[j] = *(const float4*)&xs[(rt + 16 * j) * L1S + d];
        #pragma unroll
        for (int i = 0; i < 4; ++i)
            #pragma unroll
            for (int j = 0; j < 4; ++j) {
                acc[i][j] += w4[i].x * x4[j].x;
                acc[i][j] += w4[i].y * x4[j].y;
                acc[i][j] += w4[i].z * x4[j].z;
                acc[i][j] += w4[i].w * x4[j].w;
            }
    }

    const int kcb = blockIdx.y;
    #pragma unroll
    for (int j = 0; j < 4; ++j) {
        const size_t rbase =
            (size_t)(r0 + rt + 16 * j) * (KC1 * P_N) + (size_t)kcb * P_N;
        #pragma unroll
        for (int i = 0; i < 4; ++i)
            partials[rbase + pt + 16 * i] = acc[i][j];
    }
}

// ---------------------------------------------------------------------------
// Kernel B: partial-sum + bias -> logits; top-2 routing; inline f64 softmax
// fixup for near-tie rows (reference argmaxes the fp32 softmax PROBS).
// Wave = one row's 64 parents; block = 4 rows; grid = 1024; no barriers, so
// per-wave early return is safe (suspect branch is wave-uniform).
// Slow path is COALESCED: wave = 4 parent-rows x 16 lane-positions, 16
// passes; every load covers contiguous 256B segments (r7's version was a
// 64-line gather per instruction -> 29us tail).
// ---------------------------------------------------------------------------
__global__ __launch_bounds__(256)
void hc_parent_route(const float* __restrict__ partials,
                     const float* __restrict__ pb,
                     const float* __restrict__ x,
                     const float* __restrict__ pw,
                     float* __restrict__ out_logits,
                     int* __restrict__ counts,
                     int* __restrict__ lists,
                     int* __restrict__ pclass) {
    const int tid = threadIdx.x;
    const int p   = tid & 63;
    const int w   = tid >> 6;
    const int row = blockIdx.x * 4 + w;

    // fast reduce: 16 contiguous-row partials, batched loads
    const float* prow = &partials[(size_t)row * (KC1 * P_N)];
    float lv[KC1];
    #pragma unroll
    for (int kc = 0; kc < KC1; ++kc)
        lv[kc] = prow[kc * P_N + p];
    float l = pb[p];
    #pragma unroll
    for (int kc = 0; kc < KC1; ++kc)
        l += lv[kc];

    out_logits[(size_t)row * P_N + p] = l;

    // top-2 across the wave (lanes == parents), first-max tiebreak
    float m1 = l;
    int   i1 = p;
    float m2 = NEG_INF;
    #pragma unroll
    for (int off = 32; off > 0; off >>= 1) {
        const float om1 = __shfl_xor(m1, off);
        const int   oi1 = __shfl_xor(i1, off);
        const float om2 = __shfl_xor(m2, off);
        if (om1 > m1 || (om1 == m1 && oi1 < i1)) {
            m2 = fmaxf(m1, om2);
            m1 = om1;
            i1 = oi1;
        } else {
            m2 = fmaxf(m2, om1);
        }
    }

    if (m1 - m2 > GAP_TAU) {
        if (p == 0) {
            const int pos = atomicAdd(&counts[i1], 1);
            lists[i1 * B_N + pos] = row;
            pclass[row] = i1;
        }
        return;
    }

    // ---- wave-uniform slow path: coalesced f64 logits + fp32 softmax emu --
    // lanes: g = p>>4 (parent subgroup of 4), h = p&15 (16 positions).
    // Pass pp = pass*4+g: 16 lanes cooperatively dot pw[pp] with x[row] in
    // f64 (4 split accumulators per lane breaks the FMA chain; xor-reduce
    // over h). Each lane then collects the logit for ITS parent p via shfl.
    const int g = p >> 4;
    const int h = p & 15;
    const float* xr = &x[(size_t)row * D_N];
    double myl = 0.0;
    for (int pass = 0; pass < 16; ++pass) {
        const int pp = pass * 4 + g;
        const float* wr = &pw[(size_t)pp * D_N];
        double a0 = 0.0, a1 = 0.0, a2 = 0.0, a3 = 0.0;
        #pragma unroll
        for (int ch = 0; ch < 16; ++ch) {
            const float4 wv = *(const float4*)&wr[ch * 64 + h * 4];
            const float4 xv = *(const float4*)&xr[ch * 64 + h * 4];
            a0 = fma((double)wv.x, (double)xv.x, a0);
            a1 = fma((double)wv.y, (double)xv.y, a1);
            a2 = fma((double)wv.z, (double)xv.z, a2);
            a3 = fma((double)wv.w, (double)xv.w, a3);
        }
        double a = (a0 + a1) + (a2 + a3);
        #pragma unroll
        for (int off = 8; off > 0; off >>= 1)
            a += __shfl_xor(a, off);            // all 16 lanes of group g hold it
        const double t = __shfl(a, (p & 3) << 4);  // grab from group p&3
        if (pass == (p >> 2)) myl = t;
    }
    const double accv = (double)pb[p] + myl;
    const float  l32  = (float)accv;
    float m = l32;
    #pragma unroll
    for (int off = 32; off > 0; off >>= 1)
        m = fmaxf(m, __shfl_xor(m, off));
    const float e = (float)exp((double)(l32 - m));  // correctly-rounded f32 exp
    double es = (double)e;
    #pragma unroll
    for (int off = 32; off > 0; off >>= 1)
        es += __shfl_xor(es, off);
    es = __shfl(es, 0);
    const float s    = (float)es;
    const float prob = e / s;                        // IEEE f32 divide: ties survive
    float pm = prob;
    int   pi = p;
    #pragma unroll
    for (int off = 32; off > 0; off >>= 1) {
        const float opm = __shfl_xor(pm, off);
        const int   opi = __shfl_xor(pi, off);
        if (opm > pm || (opm == pm && opi < pi)) { pm = opm; pi = opi; }
    }
    if (p == 0) {
        const int pos = atomicAdd(&counts[pi], 1);
        lists[pi * B_N + pos] = row;
        pclass[row] = pi;
    }
}

// ---------------------------------------------------------------------------
// Kernel C: child-GEMM partials, register-tiled, row-tile loop.
// Grid (64 classes, 8 K-chunks) = 512 blocks, ALL active; weights staged once
// per block, then loop over 64-row gathered tiles. Thread (jt,rt): outputs
// {jt+16i, i<3} x rows {rt+16j, j<4}. part2 layout [row][kc][j]
// (row stride KC2*NC_N = 384 floats) for reader locality.
// ---------------------------------------------------------------------------
__global__ __launch_bounds__(256, 2)
void hc_child_partial(const float* __restrict__ x,
                      const float* __restrict__ w0,
                      const float* __restrict__ w1,
                      const int* __restrict__ counts,
                      const int* __restrict__ lists,
                      float* __restrict__ part2) {
    const int c  = blockIdx.x;
    const int kc = blockIdx.y;
    const int n  = counts[c];
    const int d0 = kc * DKC2;

    __shared__ int   rl[64];
    __shared__ float xs[64 * L2S];
    __shared__ float ws[NC_N * L2S];

    const int tid = threadIdx.x;

    // stage class's 48 child-weight rows once: 1536 float4, 6 per thread
    #pragma unroll
    for (int k = 0; k < 6; ++k) {
        const int f  = tid + 256 * k;
        const int j  = f >> 5;
        const int dp = (f & 31) * 4;
        const float* src = (j < C0_N)
            ? &w0[((size_t)c * C0_N + j) * D_N + d0 + dp]
            : &w1[((size_t)c * C1_N + (j - C0_N)) * D_N + d0 + dp];
        *(float4*)&ws[j * L2S + dp] = *(const float4*)src;
    }

    const int jt = tid & 15;
    const int rt = tid >> 4;   // 0..15

    for (int t0 = 0; t0 < n; t0 += 64) {
        const int m = min(64, n - t0);
        __syncthreads();   // prior iter's xs/rl reads done
        if (tid < 64)
            rl[tid] = lists[c * B_N + t0 + (tid < m ? tid : 0)];
        __syncthreads();
        // stage gathered x rows: 64 x 128 = 2048 float4, 8 per thread
        #pragma unroll
        for (int k = 0; k < 8; ++k) {
            const int f  = tid + 256 * k;
            const int r  = f >> 5;
            const int dp = (f & 31) * 4;
            *(float4*)&xs[r * L2S + dp] =
                *(const float4*)&x[(size_t)rl[r] * D_N + d0 + dp];
        }
        __syncthreads();   // also covers the one-time ws staging

        float acc[3][4] = {};   // [i: output][j: row]
        #pragma unroll 2
        for (int d = 0; d < DKC2; d += 4) {
            float4 w4[3], x4[4];
            #pragma unroll
            for (int i = 0; i < 3; ++i)
                w4[i] = *(const float4*)&ws[(jt + 16 * i) * L2S + d];
            #pragma unroll
            for (int j = 0; j < 4; ++j)
                x4[j] = *(const float4*)&xs[(rt + 16 * j) * L2S + d];
            #pragma unroll
            for (int i = 0; i < 3; ++i)
                #pragma unroll
                for (int j = 0; j < 4; ++j) {
                    acc[i][j] += w4[i].x * x4[j].x;
                    acc[i][j] += w4[i].y * x4[j].y;
                    acc[i][j] += w4[i].z * x4[j].z;
                    acc[i][j] += w4[i].w * x4[j].w;
                }
        }

        #pragma unroll
        for (int j = 0; j < 4; ++j) {
            const int rr = rt + 16 * j;
            if (rr < m) {
                const size_t rbase =
                    (size_t)rl[rr] * (KC2 * NC_N) + (size_t)kc * NC_N;
                #pragma unroll
                for (int i = 0; i < 3; ++i)
                    part2[rbase + jt + 16 * i] = acc[i][j];
            }
        }
    }
}

// ---------------------------------------------------------------------------
// Kernel D: deterministic child partial-sum + bias -> c0/c1 outputs.
// Thread = one (row, j) of 4096 x 48; a row's 8 partials are contiguous
// (384-float row block). Grid = 768 blocks.
// ---------------------------------------------------------------------------
__global__ __launch_bounds__(256)
void hc_child_reduce(const float* __restrict__ part2,
                     const float* __restrict__ b0,
                     const float* __restrict__ b1,
                     const int* __restrict__ pclass,
                     float* __restrict__ out_c0,
                     float* __restrict__ out_c1) {
    const int t   = blockIdx.x * 256 + threadIdx.x;   // 0 .. 4096*48-1
    const int row = t / NC_N;
    const int j   = t - row * NC_N;

    const float* prow = &part2[(size_t)row * (KC2 * NC_N)];
    float lv[KC2];
    #pragma unroll
    for (int kc = 0; kc < KC2; ++kc)
        lv[kc] = prow[kc * NC_N + j];
    float v = 0.f;
    #pragma unroll
    for (int kc = 0; kc < KC2; ++kc)
        v += lv[kc];

    const int c = pclass[row];
    if (j < C0_N)
        out_c0[(size_t)row * C0_N + j] = v + b0[c * C0_N + j];
    else
        out_c1[(size_t)row * C1_N + (j - C0_N)] = v + b1[c * C1_N + (j - C0_N)];
}

// ---------------------------------------------------------------------------
extern "C" void kernel_launch(void* const* d_in, const int* in_sizes, int n_in,
                              void* d_out, int out_size, void* d_ws, size_t ws_size,
                              hipStream_t stream) {
    const float* x  = (const float*)d_in[0];
    const float* pw = (const float*)d_in[1];
    const float* pb = (const float*)d_in[2];
    const float* w0 = (const float*)d_in[3];
    const float* b0 = (const float*)d_in[4];
    const float* w1 = (const float*)d_in[5];
    const float* b1 = (const float*)d_in[6];

    float* out_logits = (float*)d_out;                       // [4096][64]
    float* out_c0     = out_logits + (size_t)B_N * P_N;      // [4096][16]
    float* out_c1     = out_c0     + (size_t)B_N * C0_N;     // [4096][32]

    // workspace (~18 MB): parent partials (16 MB) aliased with child part2
    // (6 MB) — partials fully consumed by route before C writes part2.
    int*   counts   = (int*)d_ws;              // 64
    int*   pclass   = counts + P_N;            // 4096
    int*   lists    = pclass + B_N;            // 64*4096
    float* partials = (float*)(lists + P_N * B_N);

    hc_parent_partial<<<dim3(B_N / 64, KC1), 256, 0, stream>>>(
        x, pw, partials, counts);

    hc_parent_route<<<B_N / 4, 256, 0, stream>>>(
        partials, pb, x, pw, out_logits, counts, lists, pclass);

    hc_child_partial<<<dim3(P_N, KC2), 256, 0, stream>>>(
        x, w0, w1, counts, lists, partials);

    hc_child_reduce<<<(B_N * NC_N) / 256, 256, 0, stream>>>(
        partials, b0, b1, pclass, out_c0, out_c1);
}

// Round 9
// 74.267 us; speedup vs baseline: 1.4117x; 1.4117x over previous
//
#include <hip/hip_runtime.h>
#include <hip/hip_bf16.h>

// Sizes fixed by the reference problem.
#define B_N   4096
#define D_N   1024
#define P_N   64
#define C0_N  16
#define C1_N  32
#define NC_N  48    // C0 + C1 concatenated

// parent GEMM K-split
#define KC1   16
#define DKC1  64
#define L1S   68     // 64+4: 16B-aligned rows; rows 16 apart -> 2-way bank alias (free)

// child GEMM K-split
#define KC2   8
#define DKC2  128
#define L2S   132    // 128+4: same bank math

// Tie physics: fp32 softmax probs can only tie when the true logit gap is
// <~2e-7 (exp ulp 6e-8 near 1.0; prob ulp 1.9e-9 x s~64 = 1.2e-7; exp
// rounding +-6e-8). Our fp32 gap estimate is accurate to ~1e-9. tau=1e-6
// gives 5x margin and flags only ~0.6% of rows (~26).
#define GAP_TAU 1e-6f
#define NEG_INF (-3.402823466e38f)

// ---------------------------------------------------------------------------
// Kernel A: parent-logit partials, register-tiled.
// Block = 64 rows x 64 parents x one 64-deep K-chunk; 256 threads.
// Thread (pt=tid&15, rt=tid>>4): parents {pt+16i} x rows {rt+16j}, i,j<4.
// Partials layout [row][kc][p]: a row's 16 partials are one contiguous 4KB
// block for the reader. Block (0,0) zeroes counts/nsus.
// ---------------------------------------------------------------------------
__global__ __launch_bounds__(256, 4)
void hc_parent_partial(const float* __restrict__ x,
                       const float* __restrict__ pw,
                       float* __restrict__ partials,
                       int* __restrict__ counts,
                       int* __restrict__ nsus) {
    __shared__ float xs[64 * L1S];
    __shared__ float ws[P_N * L1S];

    const int tid = threadIdx.x;
    if (blockIdx.x == 0 && blockIdx.y == 0 && tid <= P_N) {
        if (tid < P_N) counts[tid] = 0;
        else           *nsus = 0;
    }

    const int r0 = blockIdx.x * 64;
    const int d0 = blockIdx.y * DKC1;

    // stage x: 64 rows x 64 floats = 1024 float4, 4 per thread
    #pragma unroll
    for (int k = 0; k < 4; ++k) {
        const int f  = tid + 256 * k;
        const int r  = f >> 4;
        const int dp = (f & 15) * 4;
        *(float4*)&xs[r * L1S + dp] =
            *(const float4*)&x[(size_t)(r0 + r) * D_N + d0 + dp];
    }
    // stage W chunk: 64 rows x 64 floats = 1024 float4, 4 per thread
    #pragma unroll
    for (int k = 0; k < 4; ++k) {
        const int f  = tid + 256 * k;
        const int r  = f >> 4;
        const int dp = (f & 15) * 4;
        *(float4*)&ws[r * L1S + dp] =
            *(const float4*)&pw[(size_t)r * D_N + d0 + dp];
    }
    __syncthreads();

    const int pt = tid & 15;
    const int rt = tid >> 4;   // 0..15

    float acc[4][4] = {};      // [i: parent][j: row]
    #pragma unroll
    for (int d = 0; d < DKC1; d += 4) {
        float4 w4[4], x4[4];
        #pragma unroll
        for (int i = 0; i < 4; ++i)
            w4[i] = *(const float4*)&ws[(pt + 16 * i) * L1S + d];
        #pragma unroll
        for (int j = 0; j < 4; ++j)
            x4[j] = *(const float4*)&xs[(rt + 16 * j) * L1S + d];
        #pragma unroll
        for (int i = 0; i < 4; ++i)
            #pragma unroll
            for (int j = 0; j < 4; ++j) {
                acc[i][j] += w4[i].x * x4[j].x;
                acc[i][j] += w4[i].y * x4[j].y;
                acc[i][j] += w4[i].z * x4[j].z;
                acc[i][j] += w4[i].w * x4[j].w;
            }
    }

    const int kcb = blockIdx.y;
    #pragma unroll
    for (int j = 0; j < 4; ++j) {
        const size_t rbase =
            (size_t)(r0 + rt + 16 * j) * (KC1 * P_N) + (size_t)kcb * P_N;
        #pragma unroll
        for (int i = 0; i < 4; ++i)
            partials[rbase + pt + 16 * i] = acc[i][j];
    }
}

// ---------------------------------------------------------------------------
// Kernel B1: FAST routing only. Partial-sum + bias -> logits; wave top-2;
// bin directly if gap > tau, else append to suspect list (handled by B2).
// Wave = one row's 64 parents; block = 4 rows; grid = 1024. No slow-path
// code -> low VGPR, high occupancy (r8's fused version: VGPR 84, 100us).
// ---------------------------------------------------------------------------
__global__ __launch_bounds__(256)
void hc_parent_route(const float* __restrict__ partials,
                     const float* __restrict__ pb,
                     float* __restrict__ out_logits,
                     int* __restrict__ counts,
                     int* __restrict__ lists,
                     int* __restrict__ nsus,
                     int* __restrict__ suspects,
                     int* __restrict__ pclass) {
    const int tid = threadIdx.x;
    const int p   = tid & 63;
    const int w   = tid >> 6;
    const int row = blockIdx.x * 4 + w;

    const float* prow = &partials[(size_t)row * (KC1 * P_N)];
    float lv[KC1];
    #pragma unroll
    for (int kc = 0; kc < KC1; ++kc)
        lv[kc] = prow[kc * P_N + p];
    float l = pb[p];
    #pragma unroll
    for (int kc = 0; kc < KC1; ++kc)
        l += lv[kc];

    out_logits[(size_t)row * P_N + p] = l;

    // top-2 across the wave (lanes == parents), first-max tiebreak
    float m1 = l;
    int   i1 = p;
    float m2 = NEG_INF;
    #pragma unroll
    for (int off = 32; off > 0; off >>= 1) {
        const float om1 = __shfl_xor(m1, off);
        const int   oi1 = __shfl_xor(i1, off);
        const float om2 = __shfl_xor(m2, off);
        if (om1 > m1 || (om1 == m1 && oi1 < i1)) {
            m2 = fmaxf(m1, om2);
            m1 = om1;
            i1 = oi1;
        } else {
            m2 = fmaxf(m2, om1);
        }
    }

    if (p == 0) {
        if (m1 - m2 > GAP_TAU) {
            const int pos = atomicAdd(&counts[i1], 1);
            lists[i1 * B_N + pos] = row;
            pclass[row] = i1;
        } else {
            const int pos = atomicAdd(nsus, 1);
            suspects[pos] = row;
        }
    }
}

// ---------------------------------------------------------------------------
// Kernel B2: suspect fixup — one BLOCK (4 waves) per suspect row.
// Wave w handles parents [w*16, w*16+16), one parent per pass: the whole
// wave cooperatively dots pw[pp] with x[row] in f64 (lane holds its 16
// x-floats in registers across passes; 4 coalesced dwordx4 pw loads per
// pass), xor-reduces, lane 0 -> LDS. Then wave 0 emulates the reference's
// fp32 softmax off the 64 f64 logits and bins with first-index argmax.
// Grid = 64 blocks, grid-stride over suspects (~26 expected).
// ---------------------------------------------------------------------------
__global__ __launch_bounds__(256)
void hc_fixup(const float* __restrict__ x,
              const float* __restrict__ pw,
              const float* __restrict__ pb,
              const int* __restrict__ nsus,
              const int* __restrict__ suspects,
              int* __restrict__ counts,
              int* __restrict__ lists,
              int* __restrict__ pclass) {
    __shared__ double ld[P_N];

    const int tid  = threadIdx.x;
    const int lane = tid & 63;
    const int w    = tid >> 6;    // wave 0..3
    const int ns   = *nsus;

    for (int sidx = blockIdx.x; sidx < ns; sidx += gridDim.x) {
        const int row = suspects[sidx];
        __syncthreads();   // prior iteration's ld reads complete

        // lane-resident x chunk: x[row][lane*16 .. lane*16+16)
        const float* xr = &x[(size_t)row * D_N + lane * 16];
        float4 xv[4];
        #pragma unroll
        for (int k = 0; k < 4; ++k)
            xv[k] = *(const float4*)&xr[k * 4];

        #pragma unroll 2
        for (int pass = 0; pass < 16; ++pass) {
            const int pp = w * 16 + pass;
            const float* wr = &pw[(size_t)pp * D_N + lane * 16];
            double a0 = 0.0, a1 = 0.0, a2 = 0.0, a3 = 0.0;
            #pragma unroll
            for (int k = 0; k < 4; ++k) {
                const float4 wv = *(const float4*)&wr[k * 4];
                a0 = fma((double)wv.x, (double)xv[k].x, a0);
                a1 = fma((double)wv.y, (double)xv[k].y, a1);
                a2 = fma((double)wv.z, (double)xv[k].z, a2);
                a3 = fma((double)wv.w, (double)xv[k].w, a3);
            }
            double a = (a0 + a1) + (a2 + a3);
            #pragma unroll
            for (int off = 32; off > 0; off >>= 1)
                a += __shfl_xor(a, off);
            if (lane == 0) ld[pp] = a;
        }
        __syncthreads();

        if (w == 0) {
            // ---- emulate fp32 softmax + first-index argmax (wave 0) ----
            const int   p    = lane;
            const double acc = (double)pb[p] + ld[p];
            const float  l32 = (float)acc;
            float m = l32;
            #pragma unroll
            for (int off = 32; off > 0; off >>= 1)
                m = fmaxf(m, __shfl_xor(m, off));
            const float e = (float)exp((double)(l32 - m));  // correctly-rounded
            double es = (double)e;
            #pragma unroll
            for (int off = 32; off > 0; off >>= 1)
                es += __shfl_xor(es, off);
            es = __shfl(es, 0);
            const float s    = (float)es;
            const float prob = e / s;        // IEEE f32 divide: ties survive
            float pm = prob;
            int   pi = p;
            #pragma unroll
            for (int off = 32; off > 0; off >>= 1) {
                const float opm = __shfl_xor(pm, off);
                const int   opi = __shfl_xor(pi, off);
                if (opm > pm || (opm == pm && opi < pi)) { pm = opm; pi = opi; }
            }
            if (p == 0) {
                const int pos = atomicAdd(&counts[pi], 1);
                lists[pi * B_N + pos] = row;
                pclass[row] = pi;
            }
        }
    }
}

// ---------------------------------------------------------------------------
// Kernel C: child-GEMM partials, register-tiled, row-tile loop.
// Grid (64 classes, 8 K-chunks) = 512 blocks, ALL active; weights staged once
// per block, then loop over 64-row gathered tiles. Thread (jt,rt): outputs
// {jt+16i, i<3} x rows {rt+16j, j<4}. part2 layout [row][kc][j].
// ---------------------------------------------------------------------------
__global__ __launch_bounds__(256, 2)
void hc_child_partial(const float* __restrict__ x,
                      const float* __restrict__ w0,
                      const float* __restrict__ w1,
                      const int* __restrict__ counts,
                      const int* __restrict__ lists,
                      float* __restrict__ part2) {
    const int c  = blockIdx.x;
    const int kc = blockIdx.y;
    const int n  = counts[c];
    const int d0 = kc * DKC2;

    __shared__ int   rl[64];
    __shared__ float xs[64 * L2S];
    __shared__ float ws[NC_N * L2S];

    const int tid = threadIdx.x;

    // stage class's 48 child-weight rows once: 1536 float4, 6 per thread
    #pragma unroll
    for (int k = 0; k < 6; ++k) {
        const int f  = tid + 256 * k;
        const int j  = f >> 5;
        const int dp = (f & 31) * 4;
        const float* src = (j < C0_N)
            ? &w0[((size_t)c * C0_N + j) * D_N + d0 + dp]
            : &w1[((size_t)c * C1_N + (j - C0_N)) * D_N + d0 + dp];
        *(float4*)&ws[j * L2S + dp] = *(const float4*)src;
    }

    const int jt = tid & 15;
    const int rt = tid >> 4;   // 0..15

    for (int t0 = 0; t0 < n; t0 += 64) {
        const int m = min(64, n - t0);
        __syncthreads();   // prior iter's xs/rl reads done
        if (tid < 64)
            rl[tid] = lists[c * B_N + t0 + (tid < m ? tid : 0)];
        __syncthreads();
        // stage gathered x rows: 64 x 128 = 2048 float4, 8 per thread
        #pragma unroll
        for (int k = 0; k < 8; ++k) {
            const int f  = tid + 256 * k;
            const int r  = f >> 5;
            const int dp = (f & 31) * 4;
            *(float4*)&xs[r * L2S + dp] =
                *(const float4*)&x[(size_t)rl[r] * D_N + d0 + dp];
        }
        __syncthreads();   // also covers the one-time ws staging

        float acc[3][4] = {};   // [i: output][j: row]
        #pragma unroll 2
        for (int d = 0; d < DKC2; d += 4) {
            float4 w4[3], x4[4];
            #pragma unroll
            for (int i = 0; i < 3; ++i)
                w4[i] = *(const float4*)&ws[(jt + 16 * i) * L2S + d];
            #pragma unroll
            for (int j = 0; j < 4; ++j)
                x4[j] = *(const float4*)&xs[(rt + 16 * j) * L2S + d];
            #pragma unroll
            for (int i = 0; i < 3; ++i)
                #pragma unroll
                for (int j = 0; j < 4; ++j) {
                    acc[i][j] += w4[i].x * x4[j].x;
                    acc[i][j] += w4[i].y * x4[j].y;
                    acc[i][j] += w4[i].z * x4[j].z;
                    acc[i][j] += w4[i].w * x4[j].w;
                }
        }

        #pragma unroll
        for (int j = 0; j < 4; ++j) {
            const int rr = rt + 16 * j;
            if (rr < m) {
                const size_t rbase =
                    (size_t)rl[rr] * (KC2 * NC_N) + (size_t)kc * NC_N;
                #pragma unroll
                for (int i = 0; i < 3; ++i)
                    part2[rbase + jt + 16 * i] = acc[i][j];
            }
        }
    }
}

// ---------------------------------------------------------------------------
// Kernel D: deterministic child partial-sum + bias -> c0/c1 outputs.
// Thread = one (row, j) of 4096 x 48; a row's 8 partials are contiguous.
// ---------------------------------------------------------------------------
__global__ __launch_bounds__(256)
void hc_child_reduce(const float* __restrict__ part2,
                     const float* __restrict__ b0,
                     const float* __restrict__ b1,
                     const int* __restrict__ pclass,
                     float* __restrict__ out_c0,
                     float* __restrict__ out_c1) {
    const int t   = blockIdx.x * 256 + threadIdx.x;   // 0 .. 4096*48-1
    const int row = t / NC_N;
    const int j   = t - row * NC_N;

    const float* prow = &part2[(size_t)row * (KC2 * NC_N)];
    float lv[KC2];
    #pragma unroll
    for (int kc = 0; kc < KC2; ++kc)
        lv[kc] = prow[kc * NC_N + j];
    float v = 0.f;
    #pragma unroll
    for (int kc = 0; kc < KC2; ++kc)
        v += lv[kc];

    const int c = pclass[row];
    if (j < C0_N)
        out_c0[(size_t)row * C0_N + j] = v + b0[c * C0_N + j];
    else
        out_c1[(size_t)row * C1_N + (j - C0_N)] = v + b1[c * C1_N + (j - C0_N)];
}

// ---------------------------------------------------------------------------
extern "C" void kernel_launch(void* const* d_in, const int* in_sizes, int n_in,
                              void* d_out, int out_size, void* d_ws, size_t ws_size,
                              hipStream_t stream) {
    const float* x  = (const float*)d_in[0];
    const float* pw = (const float*)d_in[1];
    const float* pb = (const float*)d_in[2];
    const float* w0 = (const float*)d_in[3];
    const float* b0 = (const float*)d_in[4];
    const float* w1 = (const float*)d_in[5];
    const float* b1 = (const float*)d_in[6];

    float* out_logits = (float*)d_out;                       // [4096][64]
    float* out_c0     = out_logits + (size_t)B_N * P_N;      // [4096][16]
    float* out_c1     = out_c0     + (size_t)B_N * C0_N;     // [4096][32]

    // workspace (~18 MB): parent partials (16 MB) aliased with child part2
    // (6 MB) — partials fully consumed by route before C writes part2.
    int*   counts   = (int*)d_ws;              // 64
    int*   nsus     = counts + P_N;            // 1
    int*   suspects = nsus + 1;                // 4096
    int*   pclass   = suspects + B_N;          // 4096
    int*   lists    = pclass + B_N;            // 64*4096
    float* partials = (float*)(lists + P_N * B_N);

    hc_parent_partial<<<dim3(B_N / 64, KC1), 256, 0, stream>>>(
        x, pw, partials, counts, nsus);

    hc_parent_route<<<B_N / 4, 256, 0, stream>>>(
        partials, pb, out_logits, counts, lists, nsus, suspects, pclass);

    hc_fixup<<<64, 256, 0, stream>>>(
        x, pw, pb, nsus, suspects, counts, lists, pclass);

    hc_child_partial<<<dim3(P_N, KC2), 256, 0, stream>>>(
        x, w0, w1, counts, lists, partials);

    hc_child_reduce<<<(B_N * NC_N) / 256, 256, 0, stream>>>(
        partials, b0, b1, pclass, out_c0, out_c1);
}